// Round 1
// 353.921 us; speedup vs baseline: 1.0220x; 1.0220x over previous
//
#include <hip/hip_runtime.h>

#define NN 100000
#define NE 1600000
#define FIN 256
#define FH 64
#define FC 16

#define SCAN_CHUNK 1024
#define NB_SCAN ((NN + SCAN_CHUNK - 1) / SCAN_CHUNK)   // 98
#define NB_COUNT ((NE + 255) / 256)                    // 6250
#define NB_GEMM1 ((NN + 127) / 128)                    // 782 (128-row MFMA tiles)
#define NB_FUSED (9 * NB_GEMM1)                        // 7038: every 9th block = gemm

typedef int v2i __attribute__((ext_vector_type(2)));
typedef short s16x8 __attribute__((ext_vector_type(8)));   // 8 bf16 (4 VGPRs)
typedef float f32x4 __attribute__((ext_vector_type(4)));   // MFMA acc

__device__ __forceinline__ float4 fma4(float4 v, float w, float4 a) {
    a.x = fmaf(v.x, w, a.x); a.y = fmaf(v.y, w, a.y);
    a.z = fmaf(v.z, w, a.z); a.w = fmaf(v.w, w, a.w);
    return a;
}
__device__ __forceinline__ float4 add4(float4 a, float4 v) {
    a.x += v.x; a.y += v.y; a.z += v.z; a.w += v.w;
    return a;
}
__device__ __forceinline__ float4 xor_add4(float4 r, int m) {
    r.x += __shfl_xor(r.x, m, 64); r.y += __shfl_xor(r.y, m, 64);
    r.z += __shfl_xor(r.z, m, 64); r.w += __shfl_xor(r.w, m, 64);
    return r;
}

// RNE fp32 -> bf16 (top 16 bits)
__device__ __forceinline__ unsigned short bf16rne(float f) {
    unsigned u = __float_as_uint(f);
    u += 0x7FFFu + ((u >> 16) & 1u);
    return (unsigned short)(u >> 16);
}

// split 8 fp32 into bf16 hi + bf16 lo (hi+lo ~= fp32; dropped bits ~2^-17 rel)
__device__ __forceinline__ void split8(const float* f, s16x8& hi, s16x8& lo) {
    #pragma unroll
    for (int i = 0; i < 8; i++) {
        unsigned u = __float_as_uint(f[i]);
        unsigned short h = (unsigned short)((u + 0x7FFFu + ((u >> 16) & 1u)) >> 16);
        float l = f[i] - __uint_as_float((unsigned)h << 16);
        unsigned ul = __float_as_uint(l);
        hi[i] = (short)h;
        lo[i] = (short)((ul + 0x7FFFu + ((ul >> 16) & 1u)) >> 16);
    }
}

__device__ __forceinline__ int eidx(const int* __restrict__ ei, int f, int pos) {
    return f ? ei[2 * pos] : ei[pos];
}

// ---- PREP: W1 -> MFMA B-fragment layout (bf16 hi/lo) + int64 detect --------
// B-frag layout for mfma_f32_16x16x32_bf16: lane l holds W[k0+(l>>4)*8+i][n0+(l&15)]
// flattened: Wf[((s*4 + c)*64 + l)*8 + i],  s=K-step (k0=32s), c=col-frag (n0=16c)
__global__ __launch_bounds__(256) void prep_k(const int* __restrict__ ei,
                                              int* __restrict__ flag,
                                              const float* __restrict__ W,
                                              unsigned short* __restrict__ Whi,
                                              unsigned short* __restrict__ Wlo) {
    int b = blockIdx.x;
    if (b == 8) {
        if (threadIdx.x == 0) {
            int z = (ei[1] == 0) & (ei[3] == 0) & (ei[5] == 0) & (ei[7] == 0);
            *flag = z;   // 1 => int64 layout, 0 => int32 layout
        }
        return;
    }
    int slot = b * 256 + threadIdx.x;      // 0..2047 = (s,c,l)
    int l = slot & 63;
    int c = (slot >> 6) & 3;
    int s = slot >> 8;
    int k0 = s * 32 + (l >> 4) * 8;
    int col = c * 16 + (l & 15);
    #pragma unroll
    for (int i = 0; i < 8; i++) {
        float f = W[(k0 + i) * FH + col];
        unsigned short h = bf16rne(f);
        float lres = f - __uint_as_float((unsigned)h << 16);
        Whi[slot * 8 + i] = h;
        Wlo[slot * 8 + i] = bf16rne(lres);
    }
}

// ---- FUSED: count+rank+pack || GEMM1(MFMA), roles INTERLEAVED (b%9==8) -----
// GEMM1: h1[NN][64] = x[NN][256] @ W1, 128-row tile/block, wave = 32 rows.
// bf16 hi/lo split: acc += Ahi*Bhi + Ahi*Blo + Alo*Bhi  (fp32-grade accuracy).
// No LDS: A-frags straight from global x (32B/lane contiguous), B-frags from
// the prep_k-swizzled 64KB hi/lo tables (L1/L2-resident).
__global__ __launch_bounds__(256, 4) void fused_k(const int* __restrict__ ei,
                                                  const int* __restrict__ flag,
                                                  int* __restrict__ deg,
                                                  v2i* __restrict__ packed,
                                                  const float* __restrict__ x,
                                                  const unsigned short* __restrict__ Whi,
                                                  const unsigned short* __restrict__ Wlo,
                                                  float* __restrict__ h1) {
    const int b = blockIdx.x;
    if ((b % 9) != 8) {                       // ---- count role ----
        int cb = (b / 9) * 8 + (b % 9);
        if (cb >= NB_COUNT) return;
        int e = cb * 256 + threadIdx.x;
        if (e >= NE) return;
        int f = *flag;
        int s = eidx(ei, f, e);
        int d = eidx(ei, f, NE + e);
        int r = atomicAdd(&deg[d], 1);
        v2i p; p.x = s; p.y = d | (r << 17);  // dst<2^17, rank<2^12
        packed[e] = p;
        return;
    }
    // ---- GEMM1 role ----
    const int t = threadIdx.x;
    const int lane = t & 63;
    const int wid = t >> 6;
    const int mb = (b / 9) * 128 + wid * 32;  // wave's 32-row sub-tile
    const int lr = lane & 15;                 // A row-in-frag / D col
    const int lk = (lane >> 4) * 8;           // k offset within K-step

    int ra0 = mb + lr;
    int ra1 = mb + 16 + lr;
    const float* pa0 = x + (size_t)(ra0 < NN ? ra0 : NN - 1) * FIN + lk;
    const float* pa1 = x + (size_t)(ra1 < NN ? ra1 : NN - 1) * FIN + lk;

    f32x4 acc[2][4] = {};

    for (int s = 0; s < 8; s++) {             // K-steps of 32
        float fa0[8], fa1[8];
        float4 q;
        q = *(const float4*)(pa0 + s * 32);
        fa0[0] = q.x; fa0[1] = q.y; fa0[2] = q.z; fa0[3] = q.w;
        q = *(const float4*)(pa0 + s * 32 + 4);
        fa0[4] = q.x; fa0[5] = q.y; fa0[6] = q.z; fa0[7] = q.w;
        q = *(const float4*)(pa1 + s * 32);
        fa1[0] = q.x; fa1[1] = q.y; fa1[2] = q.z; fa1[3] = q.w;
        q = *(const float4*)(pa1 + s * 32 + 4);
        fa1[4] = q.x; fa1[5] = q.y; fa1[6] = q.z; fa1[7] = q.w;

        s16x8 a0h, a0l, a1h, a1l;
        split8(fa0, a0h, a0l);
        split8(fa1, a1h, a1l);

        #pragma unroll
        for (int c = 0; c < 4; c++) {
            s16x8 wh = *(const s16x8*)&Whi[((s * 4 + c) * 64 + lane) * 8];
            s16x8 wl = *(const s16x8*)&Wlo[((s * 4 + c) * 64 + lane) * 8];
            acc[0][c] = __builtin_amdgcn_mfma_f32_16x16x32_bf16(a0h, wh, acc[0][c], 0, 0, 0);
            acc[0][c] = __builtin_amdgcn_mfma_f32_16x16x32_bf16(a0l, wh, acc[0][c], 0, 0, 0);
            acc[0][c] = __builtin_amdgcn_mfma_f32_16x16x32_bf16(a0h, wl, acc[0][c], 0, 0, 0);
            acc[1][c] = __builtin_amdgcn_mfma_f32_16x16x32_bf16(a1h, wh, acc[1][c], 0, 0, 0);
            acc[1][c] = __builtin_amdgcn_mfma_f32_16x16x32_bf16(a1l, wh, acc[1][c], 0, 0, 0);
            acc[1][c] = __builtin_amdgcn_mfma_f32_16x16x32_bf16(a1h, wl, acc[1][c], 0, 0, 0);
        }
    }
    // D layout: col = lane&15, row = (lane>>4)*4 + v   [m89-verified]
    #pragma unroll
    for (int r = 0; r < 2; r++) {
        int rowb = mb + 16 * r + (lane >> 4) * 4;
        #pragma unroll
        for (int c = 0; c < 4; c++) {
            #pragma unroll
            for (int v = 0; v < 4; v++) {
                int row = rowb + v;
                if (row < NN)
                    h1[(size_t)row * FH + 16 * c + lr] = acc[r][c][v];
            }
        }
    }
}

// ---- scan pass 1 (+ fused dinv): per-block sums ----------------------------
__global__ __launch_bounds__(256) void scan_sum_k(const int* __restrict__ deg,
                                                  int* __restrict__ partial,
                                                  float* __restrict__ dinv) {
    __shared__ int red[256];
    int b = blockIdx.x, t = threadIdx.x;
    int base = b * SCAN_CHUNK + t * 4;
    int s = 0;
    #pragma unroll
    for (int i = 0; i < 4; i++) {
        int idx = base + i;
        if (idx < NN) {
            int dv = deg[idx];
            s += dv;
            dinv[idx] = rsqrtf((float)(dv + 1));   // +1 self-loop
        }
    }
    red[t] = s;
    __syncthreads();
    for (int off = 128; off > 0; off >>= 1) {
        if (t < off) red[t] += red[t + off];
        __syncthreads();
    }
    if (t == 0) partial[b] = red[0];
}

// ---- pre-scale h1 rows by dinv: h1'[n] = dinv[n]*h1[n] ---------------------
__global__ __launch_bounds__(256) void scale1_k(float* __restrict__ h1,
                                                const float* __restrict__ dinv) {
    int i = blockIdx.x * 256 + threadIdx.x;     // quad id over NN*16
    if (i >= NN * 16) return;
    int row = i >> 4;
    float d = dinv[row];
    float4 v = *(const float4*)&h1[i * 4];
    v.x *= d; v.y *= d; v.z *= d; v.w *= d;
    *(float4*)&h1[i * 4] = v;
}

// ---- pass 2: single small block exclusive-scans the partials ---------------
__global__ __launch_bounds__(128) void scan_part_k(int* __restrict__ partial) {
    __shared__ int s[128];
    int t = threadIdx.x;
    int v = (t < NB_SCAN) ? partial[t] : 0;
    s[t] = v; __syncthreads();
    for (int off = 1; off < 128; off <<= 1) {
        int u = (t >= off) ? s[t - off] : 0;
        __syncthreads();
        s[t] += u;
        __syncthreads();
    }
    if (t < NB_SCAN) partial[t] = s[t] - v;   // exclusive
}

// ---- pass 3: per-block local scan + offset -> row_start --------------------
__global__ __launch_bounds__(256) void scan_out_k(const int* __restrict__ deg,
                                                  const int* __restrict__ partial,
                                                  int* __restrict__ row_start) {
    __shared__ int s[256];
    int b = blockIdx.x, t = threadIdx.x;
    int base = b * SCAN_CHUNK + t * 4;
    int v[4]; int sum = 0;
    #pragma unroll
    for (int i = 0; i < 4; i++) {
        int idx = base + i;
        v[i] = (idx < NN) ? deg[idx] : 0;
        sum += v[i];
    }
    s[t] = sum; __syncthreads();
    for (int off = 1; off < 256; off <<= 1) {
        int u = (t >= off) ? s[t - off] : 0;
        __syncthreads();
        s[t] += u;
        __syncthreads();
    }
    int run = partial[b] + s[t] - sum;
    #pragma unroll
    for (int i = 0; i < 4; i++) {
        int idx = base + i;
        if (idx < NN) {
            row_start[idx] = run;
            run += v[i];
            if (idx == NN - 1) row_start[NN] = run;   // == NE
        }
    }
}

// ---- CSR fill: single pass, pure store, no atomic --------------------------
__global__ __launch_bounds__(256) void fill_k(const v2i* __restrict__ packed,
                                              const int* __restrict__ row_start,
                                              int* __restrict__ csr) {
    int e = blockIdx.x * 256 + threadIdx.x;
    if (e >= NE) return;
    v2i p = __builtin_nontemporal_load(&packed[e]);   // (src, dst|rank<<17)
    int d = p.y & 0x1FFFF;
    int r = ((unsigned)p.y) >> 17;
    csr[row_start[d] + r] = p.x;
}

// ---- FUSED agg1 + relu + GEMM2 (h1 prescaled; h2' = dinv*h2 stored) --------
__global__ __launch_bounds__(256) void agg1g_k(const int* __restrict__ csr,
                                               const int* __restrict__ row_start,
                                               const float* __restrict__ h1,
                                               const float* __restrict__ dinv,
                                               const float* __restrict__ b1,
                                               const float* __restrict__ W2,
                                               float* __restrict__ h2) {
    __shared__ float sW2[FH * FC];     // 4 KB
    __shared__ float sp[4][FH];        // per-wave relu'd agg row
    const int t = threadIdx.x;
    #pragma unroll
    for (int i = 0; i < 4; i++) sW2[t + 256 * i] = W2[t + 256 * i];
    __syncthreads();

    int wid = t >> 6;
    int n = blockIdx.x * 4 + wid;
    int lane = t & 63;
    if (n >= NN) return;
    int sg = lane >> 4;        // edge slot 0..3
    int fl = lane & 15;        // feature quad 0..15
    int s0 = row_start[n], s1 = row_start[n + 1];
    float4 A = make_float4(0.f, 0.f, 0.f, 0.f);
    float4 B = make_float4(0.f, 0.f, 0.f, 0.f);
    float4 C = make_float4(0.f, 0.f, 0.f, 0.f);
    float4 D = make_float4(0.f, 0.f, 0.f, 0.f);
    for (int j0 = s0; j0 < s1; j0 += 64) {
        int idx = j0 + lane;
        int sl = (idx < s1) ? csr[idx] : 0;
        int cnt = s1 - j0; if (cnt > 64) cnt = 64;
        int j = 0;
        for (; j + 16 <= cnt; j += 16) {
            int eA = __shfl(sl, j + sg, 64);
            int eB = __shfl(sl, j + 4 + sg, 64);
            int eC = __shfl(sl, j + 8 + sg, 64);
            int eD = __shfl(sl, j + 12 + sg, 64);
            float4 vA = *(const float4*)&h1[eA * FH + fl * 4];
            float4 vB = *(const float4*)&h1[eB * FH + fl * 4];
            float4 vC = *(const float4*)&h1[eC * FH + fl * 4];
            float4 vD = *(const float4*)&h1[eD * FH + fl * 4];
            A = add4(A, vA); B = add4(B, vB);
            C = add4(C, vC); D = add4(D, vD);
        }
        if (j + 8 <= cnt) {
            int eA = __shfl(sl, j + sg, 64);
            int eB = __shfl(sl, j + 4 + sg, 64);
            float4 vA = *(const float4*)&h1[eA * FH + fl * 4];
            float4 vB = *(const float4*)&h1[eB * FH + fl * 4];
            A = add4(A, vA); B = add4(B, vB);
            j += 8;
        }
        if (j + 4 <= cnt) {
            int eA = __shfl(sl, j + sg, 64);
            float4 vA = *(const float4*)&h1[eA * FH + fl * 4];
            A = add4(A, vA);
            j += 4;
        }
        int rem = cnt - j;
        if (rem > 0) {                      // 1..3 edges, mask extra slots
            int jj = j + (sg < rem ? sg : 0);
            int eA = __shfl(sl, jj, 64);
            float wA = (sg < rem) ? 1.f : 0.f;
            float4 vA = *(const float4*)&h1[eA * FH + fl * 4];
            A = fma4(vA, wA, A);
        }
    }
    float4 r = add4(add4(A, B), add4(C, D));
    r = xor_add4(r, 16);
    r = xor_add4(r, 32);                    // all lanes hold full quad sum
    float dn = dinv[n];
    if (sg == 0) {
        float4 self = *(const float4*)&h1[n * FH + fl * 4];   // h1' already scaled
        float4 bq = *(const float4*)&b1[fl * 4];
        float4 p;
        p.x = fmaxf(fmaf(r.x + self.x, dn, bq.x), 0.f);
        p.y = fmaxf(fmaf(r.y + self.y, dn, bq.y), 0.f);
        p.z = fmaxf(fmaf(r.z + self.z, dn, bq.z), 0.f);
        p.w = fmaxf(fmaf(r.w + self.w, dn, bq.w), 0.f);
        *(float4*)&sp[wid][fl * 4] = p;     // wave-local LDS
    }
    __builtin_amdgcn_s_waitcnt(0);          // drain lgkm within wave
    if (lane < FC) {
        float o = 0.f;
        #pragma unroll 8
        for (int k = 0; k < FH; k++)
            o = fmaf(sp[wid][k], sW2[k * FC + lane], o);
        h2[n * FC + lane] = o * dn;         // store h2' = dinv*h2
    }
}

// ---- agg layer2 (h2' prescaled): 16-lane subgroup/node, 16 edges in flight -
__global__ __launch_bounds__(256) void agg2_k(const int* __restrict__ csr,
                                              const int* __restrict__ row_start,
                                              const float* __restrict__ h2,
                                              const float* __restrict__ dinv,
                                              const float* __restrict__ b2,
                                              float* __restrict__ out) {
    const int t = threadIdx.x;
    int n = blockIdx.x * 16 + (t >> 4);
    int l16 = t & 15;
    int base = t & 48;          // subgroup base lane in wave
    int q = (t >> 2) & 3;       // edge slot
    int c = t & 3;              // feature quad
    if (n >= NN) return;
    int s0 = row_start[n], s1 = row_start[n + 1];
    float4 A = make_float4(0.f, 0.f, 0.f, 0.f);
    float4 B = make_float4(0.f, 0.f, 0.f, 0.f);
    float4 C = make_float4(0.f, 0.f, 0.f, 0.f);
    float4 D = make_float4(0.f, 0.f, 0.f, 0.f);
    for (int j0 = s0; j0 < s1; j0 += 16) {
        int idx = j0 + l16;
        int sl = (idx < s1) ? csr[idx] : 0;
        int cnt = s1 - j0; if (cnt > 16) cnt = 16;
        int j = 0;
        if (j + 16 <= cnt) {
            int eA = __shfl(sl, base + j + q, 64);
            int eB = __shfl(sl, base + j + 4 + q, 64);
            int eC = __shfl(sl, base + j + 8 + q, 64);
            int eD = __shfl(sl, base + j + 12 + q, 64);
            float4 vA = *(const float4*)&h2[eA * FC + c * 4];
            float4 vB = *(const float4*)&h2[eB * FC + c * 4];
            float4 vC = *(const float4*)&h2[eC * FC + c * 4];
            float4 vD = *(const float4*)&h2[eD * FC + c * 4];
            A = add4(A, vA); B = add4(B, vB);
            C = add4(C, vC); D = add4(D, vD);
            j += 16;
        }
        if (j + 8 <= cnt) {
            int eA = __shfl(sl, base + j + q, 64);
            int eB = __shfl(sl, base + j + 4 + q, 64);
            float4 vA = *(const float4*)&h2[eA * FC + c * 4];
            float4 vB = *(const float4*)&h2[eB * FC + c * 4];
            A = add4(A, vA); B = add4(B, vB);
            j += 8;
        }
        if (j + 4 <= cnt) {
            int eA = __shfl(sl, base + j + q, 64);
            float4 vA = *(const float4*)&h2[eA * FC + c * 4];
            A = add4(A, vA);
            j += 4;
        }
        int rem = cnt - j;
        if (rem > 0) {
            int jj = base + j + (q < rem ? q : 0);
            int eA = __shfl(sl, jj, 64);
            float wA = (q < rem) ? 1.f : 0.f;
            float4 vA = *(const float4*)&h2[eA * FC + c * 4];
            A = fma4(vA, wA, A);
        }
    }
    float4 r = add4(add4(A, B), add4(C, D));
    r = xor_add4(r, 4);
    r = xor_add4(r, 8);                     // reduce across q within subgroup
    if (q == 0) {
        float dn = dinv[n];
        float4 self = *(const float4*)&h2[n * FC + c * 4];    // h2' already scaled
        float4 bq = *(const float4*)&b2[c * 4];
        float4 p;
        p.x = fmaf(r.x + self.x, dn, bq.x);
        p.y = fmaf(r.y + self.y, dn, bq.y);
        p.z = fmaf(r.z + self.z, dn, bq.z);
        p.w = fmaf(r.w + self.w, dn, bq.w);
        *(float4*)&out[n * FC + c * 4] = p;
    }
}

extern "C" void kernel_launch(void* const* d_in, const int* in_sizes, int n_in,
                              void* d_out, int out_size, void* d_ws, size_t ws_size,
                              hipStream_t stream) {
    const float* x  = (const float*)d_in[0];
    const int*   ei = (const int*)d_in[1];
    const float* W1 = (const float*)d_in[2];
    const float* b1 = (const float*)d_in[3];
    const float* W2 = (const float*)d_in[4];
    const float* b2 = (const float*)d_in[5];
    float* out = (float*)d_out;

    char* ws = (char*)d_ws;
    int*   deg       = (int*)(ws + 0);                       // 400 KB
    int*   row_start = (int*)(ws + 512 * 1024);              // 400 KB + 4
    float* dinv      = (float*)(ws + 1024 * 1024);           // 400 KB
    int*   flag      = (int*)(ws + 1536 * 1024);             // 4 B
    int*   partial   = (int*)(ws + 1540 * 1024);             // 392 B
    unsigned short* Whi = (unsigned short*)(ws + 1544 * 1024); // 32 KB (W1 bf16 hi frags)
    unsigned short* Wlo = (unsigned short*)(ws + 1584 * 1024); // 32 KB (W1 bf16 lo frags)
    int*   csr       = (int*)(ws + 2ull * 1024 * 1024);      // 6.4 MB  [fill..agg2]
    float* h1        = (float*)(ws + 9ull * 1024 * 1024);    // 25.6 MB [fused..agg1g]
    v2i*   packed    = (v2i*)(ws + 35ull * 1024 * 1024);     // 12.8 MB [fused..fill]
    float* h2        = (float*)(ws + 35ull * 1024 * 1024);   // 6.4 MB  [agg1g..agg2]
                                                             //   aliases packed (dead)

    prep_k<<<9, 256, 0, stream>>>(ei, flag, W1, Whi, Wlo);
    (void)hipMemsetAsync(deg, 0, NN * sizeof(int), stream);
    fused_k<<<NB_FUSED, 256, 0, stream>>>(ei, flag, deg, packed, x, Whi, Wlo, h1);
    scan_sum_k<<<NB_SCAN, 256, 0, stream>>>(deg, partial, dinv);
    scale1_k<<<(NN * 16 + 255) / 256, 256, 0, stream>>>(h1, dinv);
    scan_part_k<<<1, 128, 0, stream>>>(partial);
    scan_out_k<<<NB_SCAN, 256, 0, stream>>>(deg, partial, row_start);
    fill_k<<<(NE + 255) / 256, 256, 0, stream>>>(packed, row_start, csr);

    agg1g_k<<<(NN + 3) / 4, 256, 0, stream>>>(csr, row_start, h1, dinv, b1, W2, h2);
    agg2_k<<<(NN + 15) / 16, 256, 0, stream>>>(csr, row_start, h2, dinv, b2, out);
}